// Round 9
// baseline (33451.065 us; speedup 1.0000x reference)
//
#include <hip/hip_runtime.h>
#include <stdint.h>

#define STEPS 100

// ---------------------------------------------------------------------------
// Threefry2x32 (JAX-exact, 20 rounds)
// ---------------------------------------------------------------------------
__device__ __forceinline__ uint32_t rotl32(uint32_t v, int r) {
  return (v << r) | (v >> (32 - r));
}

__device__ __forceinline__ void tf2x32(uint32_t k0, uint32_t k1,
                                       uint32_t x0, uint32_t x1,
                                       uint32_t& o0, uint32_t& o1) {
  uint32_t ks2 = k0 ^ k1 ^ 0x1BD11BDAu;
  x0 += k0; x1 += k1;
#define RND(r) { x0 += x1; x1 = rotl32(x1, (r)); x1 ^= x0; }
  RND(13) RND(15) RND(26) RND(6)
  x0 += k1;  x1 += ks2 + 1u;
  RND(17) RND(29) RND(16) RND(24)
  x0 += ks2; x1 += k0 + 2u;
  RND(13) RND(15) RND(26) RND(6)
  x0 += k0;  x1 += k1 + 3u;
  RND(17) RND(29) RND(16) RND(24)
  x0 += k1;  x1 += ks2 + 4u;
  RND(13) RND(15) RND(26) RND(6)
  x0 += ks2; x1 += k0 + 5u;
#undef RND
  o0 = x0; o1 = x1;
}

__global__ void keys_k(uint32_t* __restrict__ kb) {
  int i = threadIdx.x;
  if (i < STEPS) {
    uint32_t a, b;
    tf2x32(0u, 42u, 0u, (uint32_t)i, a, b);
    kb[2 * i] = a;
    kb[2 * i + 1] = b;
  }
}

__global__ void wt_k(const float* __restrict__ w2, float* __restrict__ wT) {
  int i = blockIdx.x * blockDim.x + threadIdx.x;
  if (i >= 25000) return;
  int oc = i / 500, q = i % 500;
  wT[q * 50 + oc] = w2[i];
}

// ---------------------------------------------------------------------------
// PERSISTENT per-sample kernel: one workgroup = one batch sample, all 100
// steps. LDS holds m2/m2s/sp1/s2(=pois) — workgroup-scope sync only; no
// cross-WG communication (scheduling-order safe). All per-output summation
// chains are verbatim R8 -> bitwise identical results.
// ---------------------------------------------------------------------------
__global__ __launch_bounds__(256) void step_all_k(
    const float* __restrict__ x, const float* __restrict__ w1,
    const float* __restrict__ wT, const uint32_t* __restrict__ kb,
    float4* __restrict__ m1g, float* __restrict__ m1sg,
    uint8_t* __restrict__ sp2g) {
  __shared__ float  m2_l[50 * 196];    // 39,200 B
  __shared__ float  m2s_l[50 * 49];    //  9,800 B
  __shared__ int8_t sp1_l[20 * 196];   //  3,920 B
  __shared__ int8_t s2_l[50 * 196];    //  9,800 B (first 784 B double as pois)

  const int b = blockIdx.x;    // sample
  const int t = threadIdx.x;

  for (int i = t; i < 50 * 196; i += 256) m2_l[i] = 0.f;
  for (int i = t; i < 50 * 49; i += 256) m2s_l[i] = 0.f;
  __syncthreads();

  for (int s = 0; s < STEPS; ++s) {
    // ---- P0: poisson spikes for this sample into s2_l[0..783] ----
    {
      uint32_t k0 = kb[2 * s], k1 = kb[2 * s + 1];
      for (int p = t; p < 784; p += 256) {
        int j = b * 784 + p;                     // JAX element index
        uint32_t o0, o1;
        tf2x32(k0, k1, 0u, (uint32_t)j, o0, o1);
        uint32_t bits = o0 ^ o1;
        float r = __uint_as_float((bits >> 9) | 0x3F800000u) - 1.0f;
        float xv = x[j];                         // coalesced (p-consecutive)
        int8_t sgn = (xv > 0.f) ? (int8_t)1 : ((xv < 0.f) ? (int8_t)-1 : (int8_t)0);
        s2_l[p] = (fabsf(xv) * 0.5f > r) ? sgn : (int8_t)0;
      }
    }
    __syncthreads();

    // ---- P1: conv1 + fire + pool1 + fire (thread = pool quad) ----
    if (t < 196) {
      int q = t, qy = q / 14, qx = q % 14;
      float acc[4][20];
#pragma unroll
      for (int tt = 0; tt < 4; ++tt)
#pragma unroll
        for (int oc = 0; oc < 20; ++oc) acc[tt][oc] = 0.f;
#pragma unroll
      for (int tt = 0; tt < 4; ++tt) {
        int y = 2 * qy + (tt >> 1);
        int xx = 2 * qx + (tt & 1);
#pragma unroll
        for (int ky = 0; ky < 5; ++ky) {
          int iy = y + ky - 2;
          if (iy < 0 || iy >= 28) continue;
#pragma unroll
          for (int kx = 0; kx < 5; ++kx) {
            int ix = xx + kx - 2;
            if (ix < 0 || ix >= 28) continue;
            float v = (float)s2_l[iy * 28 + ix];
#pragma unroll
            for (int oc = 0; oc < 20; ++oc)
              acc[tt][oc] += w1[oc * 25 + ky * 5 + kx] * v;
          }
        }
      }
#pragma unroll
      for (int oc = 0; oc < 20; ++oc) {
        int gi = (b * 20 + oc) * 196 + q;
        float4 mv = m1g[gi];                     // 16B coalesced RMW
        float* mc = reinterpret_cast<float*>(&mv);
        float s4[4];
#pragma unroll
        for (int tt = 0; tt < 4; ++tt) {
          float m = mc[tt] + acc[tt][oc];
          float sp = 0.f;
          if (m > 1.0f) { sp = 1.f; m = 0.f; }
          mc[tt] = m;
          s4[tt] = sp;
        }
        m1g[gi] = mv;
        float a = 0.25f * (((s4[0] + s4[1]) + s4[2]) + s4[3]);
        float mm = m1sg[gi] + a;
        int8_t spp = 0;
        if (mm > 0.75f) { spp = 1; mm = 0.f; }
        m1sg[gi] = mm;
        sp1_l[oc * 196 + q] = spp;
      }
    }
    __syncthreads();

    // ---- P2: conv2 + fire (thread = output pixel) ----
    if (t < 196) {
      int px = t, y = px / 14, xx = px % 14;
      float acc[50];
#pragma unroll
      for (int oc = 0; oc < 50; ++oc) acc[oc] = 0.f;
      for (int ic = 0; ic < 20; ++ic) {
#pragma unroll
        for (int ky = 0; ky < 5; ++ky) {
          int iy = y + ky - 2;
          if (iy < 0 || iy >= 14) continue;
#pragma unroll
          for (int kx = 0; kx < 5; ++kx) {
            int ix = xx + kx - 2;
            if (ix < 0 || ix >= 14) continue;
            float v = (float)sp1_l[ic * 196 + iy * 14 + ix];
            const float* wrow = wT + (ic * 25 + ky * 5 + kx) * 50;
#pragma unroll
            for (int oc = 0; oc < 50; ++oc)
              acc[oc] += wrow[oc] * v;
          }
        }
      }
#pragma unroll
      for (int oc = 0; oc < 50; ++oc) {
        int li = oc * 196 + px;
        float m = m2_l[li] + acc[oc];
        int8_t sp = 0;
        if (m > 1.0f) { sp = 1; m = 0.f; }
        m2_l[li] = m;
        s2_l[li] = sp;
      }
    }
    __syncthreads();

    // ---- P3: pool2 + fire, store sp2 byte to global [s][k][b] ----
    for (int e = t; e < 2450; e += 256) {
      int oc = e / 49, q = e % 49;
      int yo = q / 7, xo = q % 7;
      int ib = oc * 196 + 2 * yo * 14 + 2 * xo;
      float s00 = (float)s2_l[ib];
      float s01 = (float)s2_l[ib + 1];
      float s10 = (float)s2_l[ib + 14];
      float s11 = (float)s2_l[ib + 15];
      float a = 0.25f * (((s00 + s01) + s10) + s11);
      float m = m2s_l[e] + a;
      uint8_t sp = 0;
      if (m > 0.75f) { sp = 1; m = 0.f; }
      m2s_l[e] = m;
      sp2g[(s * 2450 + e) * 512 + b] = sp;
    }
    __syncthreads();   // protects s2_l reuse as pois next step
  }
}

// ---------------------------------------------------------------------------
// fc0 over ALL steps, factored out of the loop. Thread = (n,b); mf0/Tf0 live
// in registers across s. k ascending, unroll-10 -> bit-identical to R8.
// ---------------------------------------------------------------------------
__global__ __launch_bounds__(256) void fc0f_k(
    const uint8_t* __restrict__ sp2g, const float* __restrict__ wf0,
    float* __restrict__ Tf0g) {
  int n = blockIdx.x >> 1;                        // 0..199 (block-uniform)
  int b = ((blockIdx.x & 1) << 8) + threadIdx.x;  // 0..511
  const float* w0 = wf0 + n * 2450;               // scalar-pipe loads
  float m = 0.f, T = 0.f;
  for (int s = 0; s < STEPS; ++s) {
    float acc = 0.f;
    for (int k0 = 0; k0 < 2450; k0 += 10) {       // 2450 = 245*10
      float v[10];
#pragma unroll
      for (int u = 0; u < 10; ++u)
        v[u] = (float)sp2g[(s * 2450 + k0 + u) * 512 + b];  // 64B coalesced
#pragma unroll
      for (int u = 0; u < 10; ++u)
        acc += w0[k0 + u] * v[u];
    }
    m += acc;
    if (m > 1.0f) { T += 1.f; m = 0.f; }
  }
  Tf0g[n * 512 + b] = T;
}

// ---------------------------------------------------------------------------
// final: out[b][i] = (Tf0[.][b] . wf1[i][.]) / 1 / 100   (j ascending)
// ---------------------------------------------------------------------------
__global__ void fc1_k(const float* __restrict__ Tf0,
                      const float* __restrict__ wf1,
                      float* __restrict__ out) {
  int idx = blockIdx.x * blockDim.x + threadIdx.x;
  if (idx >= 5120) return;
  int b = idx / 10, i = idx % 10;
  float a = 0.f;
  for (int j = 0; j < 200; ++j) a += Tf0[j * 512 + b] * wf1[i * 200 + j];
  out[idx] = (a / 1.0f) / 100.0f;
}

// ---------------------------------------------------------------------------
// Fallback path (R8-proven multi-kernel), used only if ws_size is too small.
// ---------------------------------------------------------------------------
__global__ void pois_k(const float* __restrict__ x,
                       const uint32_t* __restrict__ kb, int step,
                       int8_t* __restrict__ pois) {
  int t = blockIdx.x * blockDim.x + threadIdx.x;
  if (t >= 401408) return;
  int p = t >> 9, b = t & 511;
  int j = b * 784 + p;
  uint32_t k0 = kb[2 * step], k1 = kb[2 * step + 1];
  uint32_t o0, o1;
  tf2x32(k0, k1, 0u, (uint32_t)j, o0, o1);
  uint32_t bits = o0 ^ o1;
  float r = __uint_as_float((bits >> 9) | 0x3F800000u) - 1.0f;
  float xv = x[j];
  int8_t sgn = (xv > 0.f) ? (int8_t)1 : ((xv < 0.f) ? (int8_t)-1 : (int8_t)0);
  pois[t] = (fabsf(xv) * 0.5f > r) ? sgn : (int8_t)0;
}

__global__ __launch_bounds__(256) void c1_k(
    const int8_t* __restrict__ pois, const float* __restrict__ w1,
    float* __restrict__ m1, float* __restrict__ m1s,
    uint8_t* __restrict__ sp1) {
  int q = blockIdx.x >> 1;
  int b = ((blockIdx.x & 1) << 8) + threadIdx.x;
  int qy = q / 14, qx = q % 14;
  float acc[4][20];
#pragma unroll
  for (int t = 0; t < 4; ++t)
#pragma unroll
    for (int oc = 0; oc < 20; ++oc) acc[t][oc] = 0.f;
#pragma unroll
  for (int t = 0; t < 4; ++t) {
    int y = 2 * qy + (t >> 1);
    int xx = 2 * qx + (t & 1);
#pragma unroll
    for (int ky = 0; ky < 5; ++ky) {
      int iy = y + ky - 2;
      if (iy < 0 || iy >= 28) continue;
#pragma unroll
      for (int kx = 0; kx < 5; ++kx) {
        int ix = xx + kx - 2;
        if (ix < 0 || ix >= 28) continue;
        float v = (float)pois[(iy * 28 + ix) * 512 + b];
#pragma unroll
        for (int oc = 0; oc < 20; ++oc)
          acc[t][oc] += w1[oc * 25 + ky * 5 + kx] * v;
      }
    }
  }
#pragma unroll
  for (int oc = 0; oc < 20; ++oc) {
    float s4[4];
#pragma unroll
    for (int t = 0; t < 4; ++t) {
      int y = 2 * qy + (t >> 1);
      int xx = 2 * qx + (t & 1);
      int idx = (oc * 784 + y * 28 + xx) * 512 + b;
      float m = m1[idx] + acc[t][oc];
      float sp = 0.f;
      if (m > 1.0f) { sp = 1.f; m = 0.f; }
      m1[idx] = m;
      s4[t] = sp;
    }
    float a = 0.25f * (((s4[0] + s4[1]) + s4[2]) + s4[3]);
    int pidx = (oc * 196 + q) * 512 + b;
    float mm = m1s[pidx] + a;
    uint8_t spp = 0;
    if (mm > 0.75f) { spp = 1; mm = 0.f; }
    m1s[pidx] = mm;
    sp1[pidx] = spp;
  }
}

__global__ __launch_bounds__(256) void c2_k(
    const uint8_t* __restrict__ sp1, const float* __restrict__ wT,
    float* __restrict__ m2, uint8_t* __restrict__ s2) {
  int p = blockIdx.x >> 1;
  int b = ((blockIdx.x & 1) << 8) + threadIdx.x;
  int y = p / 14, xx = p % 14;
  float acc[50];
#pragma unroll
  for (int oc = 0; oc < 50; ++oc) acc[oc] = 0.f;
  for (int ic = 0; ic < 20; ++ic) {
#pragma unroll
    for (int ky = 0; ky < 5; ++ky) {
      int iy = y + ky - 2;
      if (iy < 0 || iy >= 14) continue;
#pragma unroll
      for (int kx = 0; kx < 5; ++kx) {
        int ix = xx + kx - 2;
        if (ix < 0 || ix >= 14) continue;
        float v = (float)sp1[(ic * 196 + iy * 14 + ix) * 512 + b];
        const float* wrow = wT + (ic * 25 + ky * 5 + kx) * 50;
#pragma unroll
        for (int oc = 0; oc < 50; ++oc)
          acc[oc] += wrow[oc] * v;
      }
    }
  }
#pragma unroll
  for (int oc = 0; oc < 50; ++oc) {
    int idx = (oc * 196 + p) * 512 + b;
    float m = m2[idx] + acc[oc];
    uint8_t sp = 0;
    if (m > 1.0f) { sp = 1; m = 0.f; }
    m2[idx] = m;
    s2[idx] = sp;
  }
}

__global__ void p2_k(const uint8_t* __restrict__ s2, float* __restrict__ m2s,
                     uint8_t* __restrict__ sp2) {
  int t = blockIdx.x * blockDim.x + threadIdx.x;
  if (t >= 1254400) return;
  int b = t & 511;
  int r = t >> 9;
  int c = r / 49, qq = r % 49;
  int yo = qq / 7, xo = qq % 7;
  int ibase = (c * 196 + 2 * yo * 14 + 2 * xo) * 512 + b;
  float s00 = (float)s2[ibase];
  float s01 = (float)s2[ibase + 512];
  float s10 = (float)s2[ibase + 14 * 512];
  float s11 = (float)s2[ibase + 14 * 512 + 512];
  float a = 0.25f * (((s00 + s01) + s10) + s11);
  float m = m2s[t] + a;
  uint8_t sp = 0;
  if (m > 0.75f) { sp = 1; m = 0.f; }
  m2s[t] = m;
  sp2[t] = sp;
}

__global__ __launch_bounds__(256) void fc0_k(
    const uint8_t* __restrict__ sp2, const float* __restrict__ wf0,
    float* __restrict__ mf0, float* __restrict__ Tf0) {
  int n = blockIdx.x >> 1;
  int b = ((blockIdx.x & 1) << 8) + threadIdx.x;
  const float* w0 = wf0 + n * 2450;
  float acc = 0.f;
  for (int k0 = 0; k0 < 2450; k0 += 10) {
    float v[10];
#pragma unroll
    for (int u = 0; u < 10; ++u)
      v[u] = (float)sp2[(k0 + u) * 512 + b];
#pragma unroll
    for (int u = 0; u < 10; ++u)
      acc += w0[k0 + u] * v[u];
  }
  int idx = n * 512 + b;
  float m = mf0[idx] + acc;
  float sp = 0.f;
  if (m > 1.0f) { sp = 1.f; m = 0.f; }
  mf0[idx] = m;
  Tf0[idx] += sp;
}

// ---------------------------------------------------------------------------
extern "C" void kernel_launch(void* const* d_in, const int* in_sizes, int n_in,
                              void* d_out, int out_size, void* d_ws, size_t ws_size,
                              hipStream_t stream) {
  (void)in_sizes; (void)n_in; (void)out_size;
  const float* x   = (const float*)d_in[0];
  const float* w1  = (const float*)d_in[1];
  const float* w2  = (const float*)d_in[2];
  const float* wf0 = (const float*)d_in[3];
  const float* wf1 = (const float*)d_in[4];
  float* out = (float*)d_out;
  char* ws = (char*)d_ws;

  // ---- main-path workspace layout (bytes) ----
  const size_t m1g_b  = 512ull * 20 * 196 * 16;   // 32,112,640 (float4/quad)
  const size_t m1sg_b = 512ull * 20 * 196 * 4;    //  8,028,160
  const size_t tf0_b  = 200ull * 512 * 4;         //    409,600
  const size_t wt_b   = 25000ull * 4;             //    100,000
  const size_t key_b  = 1024;
  const size_t sp2_b  = 100ull * 2450 * 512;      // 125,440,000
  const size_t need = m1g_b + m1sg_b + tf0_b + wt_b + key_b + sp2_b;

  if (ws_size >= need) {
    float4*   m1g  = (float4*)ws;
    float*    m1sg = (float*)(ws + m1g_b);
    float*    Tf0g = (float*)(ws + m1g_b + m1sg_b);
    float*    wT   = (float*)(ws + m1g_b + m1sg_b + tf0_b);
    uint32_t* kb   = (uint32_t*)(ws + m1g_b + m1sg_b + tf0_b + wt_b);
    uint8_t*  sp2g = (uint8_t*)(ws + m1g_b + m1sg_b + tf0_b + wt_b + key_b);

    hipMemsetAsync(ws, 0, m1g_b + m1sg_b, stream);   // zero m1/m1s only
    keys_k<<<1, 128, 0, stream>>>(kb);
    wt_k<<<98, 256, 0, stream>>>(w2, wT);
    step_all_k<<<512, 256, 0, stream>>>(x, w1, wT, kb, m1g, m1sg, sp2g);
    fc0f_k<<<400, 256, 0, stream>>>(sp2g, wf0, Tf0g);
    fc1_k<<<20, 256, 0, stream>>>(Tf0g, wf1, out);
    return;
  }

  // ---- fallback: R8-proven multi-kernel path ----
  float* m1   = (float*)ws;
  float* m1s  = m1   + 8028160;
  float* m2   = m1s  + 2007040;
  float* m2s  = m2   + 5017600;
  float* mf0  = m2s  + 1254400;
  float* Tf0  = mf0  + 102400;
  const size_t state_f = 8028160 + 2007040 + 5017600 + 1254400 + 102400 + 102400;
  float* wT   = Tf0  + 102400;
  uint32_t* keybuf = (uint32_t*)(wT + 25000);
  int8_t*  pois = (int8_t*)(keybuf + 256);
  uint8_t* sp1  = (uint8_t*)(pois + 401408);
  uint8_t* s2   = sp1 + 2007040;
  uint8_t* sp2  = s2  + 5017600;

  hipMemsetAsync(ws, 0, state_f * sizeof(float), stream);
  keys_k<<<1, 128, 0, stream>>>(keybuf);
  wt_k<<<98, 256, 0, stream>>>(w2, wT);
  for (int s = 0; s < STEPS; ++s) {
    pois_k<<<1568, 256, 0, stream>>>(x, keybuf, s, pois);
    c1_k<<<392, 256, 0, stream>>>(pois, w1, m1, m1s, sp1);
    c2_k<<<392, 256, 0, stream>>>(sp1, wT, m2, s2);
    p2_k<<<4900, 256, 0, stream>>>(s2, m2s, sp2);
    fc0_k<<<400, 256, 0, stream>>>(sp2, wf0, mf0, Tf0);
  }
  fc1_k<<<20, 256, 0, stream>>>(Tf0, wf1, out);
}